// Round 15
// baseline (231.308 us; speedup 1.0000x reference)
//
#include <hip/hip_runtime.h>

// Two-pass 3x3 VALID conv:
//  pass 1 (pack_gll): x fp32 [16][2048][2048] -> xt bf16 [h][w][16ci] in d_ws.
//    Reads go through global_load_lds (the only proven >5TB/s path):
//    stage [16ci][512w] fp32 row-chunk into 32KB LDS (chunk=[ci][w-quad],
//    1KB-contiguous per wave), barrier, then per-thread 16 lane-linear
//    ds_read_b32 + 8 pk2 + 32B contiguous xt store (R13-verified layout:
//    ci-half 16B chunks swapped when (w&4)).
//  pass 2 (conv3x3_mfma2): R5/R13-proven conv (~65us): per 32x32 tile stage
//    34x34x16ci via global_load_lds(16B) from xt, 5x mfma_16x16x32_bf16
//    per 16x16 sub-tile. Weight fragments precomputed into d_ws.

#define HIN   2048
#define WIN   2048
#define HOUT  2046
#define WOUT  2046
#define PLANE_IN  (HIN * WIN)
#define PLANE_OUT (HOUT * WOUT)
#define CTR 34
#define CTC 34
#define NCHUNK (CTR * CTC * 2)          // 2312 16B-chunks per conv tile
#define TR 34
#define TC 36                           // fused-fallback staging stride
#define XT_U32 ((size_t)HIN * WIN * 8)  // xt as u32 count (128 MiB)
#define WF_U32 (5 * 64 * 4)

typedef __attribute__((ext_vector_type(8))) short bf16x8;
typedef __attribute__((ext_vector_type(4))) float f32x4;
typedef __attribute__((ext_vector_type(4))) unsigned u32x4;
typedef f32x4 __attribute__((aligned(4))) f32x4_u;

static __device__ __forceinline__ short f2bf(float f) {
    unsigned u = __float_as_uint(f);
    return (short)((u + 0x7FFFu + ((u >> 16) & 1u)) >> 16);   // RNE
}
static __device__ __forceinline__ unsigned pk2(float lo, float hi) {
    unsigned a = __float_as_uint(lo);
    unsigned b = __float_as_uint(hi);
    a = (a + 0x7FFFu + ((a >> 16) & 1u)) >> 16;
    b = (b + 0x7FFFu + ((b >> 16) & 1u)) & 0xFFFF0000u;
    return a | b;
}

// ---------------- setup: per-lane MFMA weight fragments ----------------------
__global__ __launch_bounds__(64)
void wf_setup(const float* __restrict__ k, unsigned* __restrict__ wfbuf) {
    int lane = threadIdx.x;
    int m = lane & 15, g = lane >> 4;
    #pragma unroll
    for (int i = 0; i < 5; ++i) {
        u32x4 q;
        #pragma unroll
        for (int jj = 0; jj < 4; ++jj) {
            unsigned r = 0;
            #pragma unroll
            for (int e = 0; e < 2; ++e) {
                int kk  = 32 * i + 8 * g + 2 * jj + e;
                int tap = kk >> 4;
                int ci  = kk & 15;
                unsigned v = 0;
                if (tap < 9) v = (unsigned short)f2bf(k[(m * 16 + ci) * 9 + tap]);
                r |= v << (16 * e);
            }
            q[jj] = r;
        }
        *(u32x4*)(wfbuf + (i * 64 + lane) * 4) = q;
    }
}

// ---------------- pass 1: gll-staged transpose pack --------------------------
// Block owns (h, 512-w chunk). Stage [16ci][512w] fp32 via global_load_lds
// (chunk c = ci*128 + wquad; per-wave 64 consecutive chunks = 1KB contiguous
// per ci-run). Then thread t converts position w0+t: 16 lane-linear
// ds_read_b32, 8 pk2, 2x16B stores (32B/thread contiguous-strided).
__global__ __launch_bounds__(512, 8)
void pack_gll(const float* __restrict__ x, unsigned* __restrict__ xt) {
    __shared__ unsigned lds[16 * 512];   // 32 KB: f32 [ci][w-local]

    const int tid = threadIdx.x;
    const int wv  = tid >> 6;
    const int h   = blockIdx.x >> 2;
    const int w0  = (blockIdx.x & 3) << 9;

    // ---- stage: 2048 16B chunks, 4 gll per thread, linear LDS dest ----
    #pragma unroll
    for (int p = 0; p < 4; ++p) {
        int c  = p * 512 + tid;              // = wave-uniform base + lane
        int ci = c >> 7;
        int q  = c & 127;
        const float* src = x + (size_t)ci * PLANE_IN + (size_t)h * WIN + w0 + 4 * q;
        __builtin_amdgcn_global_load_lds(
            (const __attribute__((address_space(1))) unsigned*)src,
            (__attribute__((address_space(3))) unsigned*)&lds[(p * 512 + wv * 64) * 4],
            16, 0, 0);
    }

    __syncthreads();

    // ---- convert + store: thread t owns position w0 + t ----
    float v[16];
    #pragma unroll
    for (int ci = 0; ci < 16; ++ci)
        v[ci] = __uint_as_float(lds[ci * 512 + tid]);   // lane-linear, no conflict

    u32x4 lo, hi;
    #pragma unroll
    for (int p = 0; p < 4; ++p) {
        lo[p] = pk2(v[2 * p],     v[2 * p + 1]);
        hi[p] = pk2(v[2 * p + 8], v[2 * p + 9]);
    }
    int sw = (tid & 4) ? 4 : 0;                         // (w & 4), w0 % 8 == 0
    unsigned* op = xt + ((size_t)h * WIN + w0 + tid) * 8;
    *(u32x4*)(op + sw)       = lo;                      // ci0-7
    *(u32x4*)(op + (4 - sw)) = hi;                      // ci8-15
}

// ---------------- pass 2: MFMA conv (R5/R13-proven, gll from xt) -------------
__global__ __launch_bounds__(512, 8)
void conv3x3_mfma2(const unsigned* __restrict__ xt,
                   const unsigned* __restrict__ wfbuf,
                   float* __restrict__ out) {
    __shared__ unsigned lds[NCHUNK * 4];   // 36992 B, linear [row][col][ci-chunk]

    const int tid  = threadIdx.x;
    const int lane = tid & 63;
    const int wv   = tid >> 6;
    const int m    = lane & 15;
    const int g    = lane >> 4;

    int bid = blockIdx.x;
    int swz = (bid & 7) * 512 + (bid >> 3);    // XCD-chunked (4096 % 8 == 0)
    int h0 = (swz >> 6) * 32; if (h0 > HOUT - 32) h0 = HOUT - 32;  // 2014
    int w0 = (swz & 63) * 32;

    // ---- stage tile: 2312 chunks of 16B, linear LDS dest, per-lane gsrc ----
    {
        int base = wv * 64;
        #pragma unroll
        for (int pass = 0; pass < 4; ++pass) {
            int c   = pass * 512 + tid;
            int row = (c * 964) >> 16;          // c/68, exact for c<2312
            int sub = c - row * 68;
            int w   = w0 + (sub >> 1); if (w > WIN - 1) w = WIN - 1;
            const unsigned* src = xt + ((size_t)(h0 + row) * WIN + w) * 8 + (sub & 1) * 4;
            __builtin_amdgcn_global_load_lds(
                (const __attribute__((address_space(1))) unsigned*)src,
                (__attribute__((address_space(3))) unsigned*)&lds[(pass * 512 + base) * 4],
                16, 0, 0);
        }
        if (tid < 264) {                        // tail: chunks 2048+tid .. 2311
            int c   = 2048 + tid;
            int row = (c * 964) >> 16;
            int sub = c - row * 68;
            int w   = w0 + (sub >> 1); if (w > WIN - 1) w = WIN - 1;
            const unsigned* src = xt + ((size_t)(h0 + row) * WIN + w) * 8 + (sub & 1) * 4;
            __builtin_amdgcn_global_load_lds(
                (const __attribute__((address_space(1))) unsigned*)src,
                (__attribute__((address_space(3))) unsigned*)&lds[(2048 + base) * 4],
                16, 0, 0);
        }
    }

    // ---- weight fragments: 5 coalesced 16B loads (overlap staging) ----
    bf16x8 wf[5];
    #pragma unroll
    for (int i = 0; i < 5; ++i)
        wf[i] = *(const bf16x8*)(wfbuf + (i * 64 + lane) * 4);

    // ---- per-lane A-fragment LDS byte offsets ----
    int off[5];
    #pragma unroll
    for (int i = 0; i < 5; ++i) {
        int tap = 2 * i + (g >> 1);
        if (tap > 8) tap = 8;                   // dead K (weights are 0)
        int kh = tap / 3;
        int kw = tap - kh * 3;
        int col = m + kw;
        int o = (kh * CTC + col) * 32 + (g & 1) * 16;
        off[i] = o ^ ((col & 4) << 2);          // matches xt pre-swizzle
    }

    __syncthreads();

    const char* ldsb = (const char*)lds;

    #pragma unroll
    for (int hl4 = 0; hl4 < 4; ++hl4) {
        int hl = wv * 4 + hl4;                  // h always < HOUT (h0 <= 2014)
        int h  = h0 + hl;
        #pragma unroll
        for (int nh = 0; nh < 2; ++nh) {
            int wl = nh * 16;
            int tb = (hl * CTC + wl) * 32;
            f32x4 acc = {0.f, 0.f, 0.f, 0.f};
            #pragma unroll
            for (int i = 0; i < 5; ++i) {
                bf16x8 a = *(const bf16x8*)(ldsb + (tb + off[i]));
                acc = __builtin_amdgcn_mfma_f32_16x16x32_bf16(a, wf[i], acc, 0, 0, 0);
            }
            // D: row = g*4+r = spatial, col = m = co  ->  float4 store
            int w = w0 + wl + g * 4;
            float* op = out + m * (size_t)PLANE_OUT + (size_t)h * WOUT + w;
            if (w + 3 < WOUT) {
                *(f32x4_u*)op = acc;
            } else {
                #pragma unroll
                for (int r = 0; r < 4; ++r)
                    if (w + r < WOUT) op[r] = acc[r];
            }
        }
    }
}

// ---------------- fallback A: reg-staged fused (R9, proven 152us total) ------
__global__ __launch_bounds__(512, 8)
void conv3x3_fused(const float* __restrict__ x,
                   const unsigned* __restrict__ wfbuf,
                   float* __restrict__ out) {
    __shared__ unsigned slds[TR * TC * 8];

    const int tid  = threadIdx.x;
    const int lane = tid & 63;
    const int wv   = tid >> 6;
    const int m    = lane & 15;
    const int g    = lane >> 4;

    int bid = blockIdx.x;
    int swz = (bid & 7) * 512 + (bid >> 3);
    int h0 = (swz >> 6) * 32; if (h0 > HOUT - 32) h0 = HOUT - 32;
    int w0 = (swz & 63) * 32;

#define STAGE_TASK(T) do {                                                    \
        int t   = (T);                                                        \
        int q   = t % 9;                                                      \
        int r2  = t / 9;                                                      \
        int cih = r2 & 1;                                                     \
        int row = r2 >> 1;                                                    \
        int c   = 4 * q;                                                      \
        int w   = w0 + c; if (w > WIN - 4) w = WIN - 4;                       \
        const float* gp = x + (size_t)(cih * 8) * PLANE_IN                    \
                            + (size_t)(h0 + row) * WIN + w;                   \
        f32x4 f0 = *(const f32x4*)(gp + 0 * (size_t)PLANE_IN);                \
        f32x4 f1 = *(const f32x4*)(gp + 1 * (size_t)PLANE_IN);                \
        f32x4 f2 = *(const f32x4*)(gp + 2 * (size_t)PLANE_IN);                \
        f32x4 f3 = *(const f32x4*)(gp + 3 * (size_t)PLANE_IN);                \
        f32x4 f4 = *(const f32x4*)(gp + 4 * (size_t)PLANE_IN);                \
        f32x4 f5 = *(const f32x4*)(gp + 5 * (size_t)PLANE_IN);                \
        f32x4 f6 = *(const f32x4*)(gp + 6 * (size_t)PLANE_IN);                \
        f32x4 f7 = *(const f32x4*)(gp + 7 * (size_t)PLANE_IN);                \
        int a = ((row * TC + c) * 32 + cih * 16) ^ ((c & 4) << 2);            \
        u32x4 ch;                                                             \
        ch[0] = pk2(f0[0], f1[0]); ch[1] = pk2(f2[0], f3[0]);                 \
        ch[2] = pk2(f4[0], f5[0]); ch[3] = pk2(f6[0], f7[0]);                 \
        *(u32x4*)((char*)slds + a)      = ch;                                 \
        ch[0] = pk2(f0[1], f1[1]); ch[1] = pk2(f2[1], f3[1]);                 \
        ch[2] = pk2(f4[1], f5[1]); ch[3] = pk2(f6[1], f7[1]);                 \
        *(u32x4*)((char*)slds + a + 32) = ch;                                 \
        ch[0] = pk2(f0[2], f1[2]); ch[1] = pk2(f2[2], f3[2]);                 \
        ch[2] = pk2(f4[2], f5[2]); ch[3] = pk2(f6[2], f7[2]);                 \
        *(u32x4*)((char*)slds + a + 64) = ch;                                 \
        ch[0] = pk2(f0[3], f1[3]); ch[1] = pk2(f2[3], f3[3]);                 \
        ch[2] = pk2(f4[3], f5[3]); ch[3] = pk2(f6[3], f7[3]);                 \
        *(u32x4*)((char*)slds + a + 96) = ch;                                 \
    } while (0)

    STAGE_TASK(tid);
    if (tid < TR * 9 * 2 - 512) STAGE_TASK(512 + tid);
#undef STAGE_TASK

    bf16x8 wf[5];
    #pragma unroll
    for (int i = 0; i < 5; ++i)
        wf[i] = *(const bf16x8*)(wfbuf + (i * 64 + lane) * 4);

    int off[5];
    #pragma unroll
    for (int i = 0; i < 5; ++i) {
        int tap = 2 * i + (g >> 1);
        if (tap > 8) tap = 8;
        int kh = tap / 3;
        int kw = tap - kh * 3;
        int col = m + kw;
        int o = (kh * TC + col) * 32 + (g & 1) * 16;
        off[i] = o ^ ((col & 4) << 2);
    }

    __syncthreads();

    const char* ldsb = (const char*)slds;

    #pragma unroll
    for (int hl4 = 0; hl4 < 4; ++hl4) {
        int hl = wv * 4 + hl4;
        int h  = h0 + hl;
        #pragma unroll
        for (int nh = 0; nh < 2; ++nh) {
            int wl = nh * 16;
            int tb = (hl * TC + wl) * 32;
            f32x4 acc = {0.f, 0.f, 0.f, 0.f};
            #pragma unroll
            for (int i = 0; i < 5; ++i) {
                bf16x8 a = *(const bf16x8*)(ldsb + (tb + off[i]));
                acc = __builtin_amdgcn_mfma_f32_16x16x32_bf16(a, wf[i], acc, 0, 0, 0);
            }
            int w = w0 + wl + g * 4;
            float* op = out + m * (size_t)PLANE_OUT + (size_t)h * WOUT + w;
            if (w + 3 < WOUT) {
                *(f32x4_u*)op = acc;
            } else {
                #pragma unroll
                for (int r = 0; r < 4; ++r)
                    if (w + r < WOUT) op[r] = acc[r];
            }
        }
    }
}

// ---------------- fallback B (no workspace): fp32-staged single pass ---------
__global__ __launch_bounds__(256, 4)
void conv3x3_mfma(const float* __restrict__ x,
                  const float* __restrict__ k,
                  float* __restrict__ out) {
    __shared__ short lds2[TR * 34 * 16];
    const int tid  = threadIdx.x;
    const int lane = tid & 63;
    const int wv   = tid >> 6;
    const int m    = lane & 15;
    const int g    = lane >> 4;
    int bid = blockIdx.x;
    int swz = (bid & 7) * 512 + (bid >> 3);
    int h0 = (swz >> 6) * 32;
    int w0 = (swz & 63) * 32;
    for (int p = tid; p < TR * 34; p += 256) {
        int r = p / 34, c = p - r * 34;
        int hh = h0 + r; if (hh > HIN - 1) hh = HIN - 1;
        int ww = w0 + c; if (ww > WIN - 1) ww = WIN - 1;
        const float* gp = x + hh * WIN + ww;
        short t[16];
        #pragma unroll
        for (int ci = 0; ci < 16; ++ci) t[ci] = f2bf(gp[ci * PLANE_IN]);
        bf16x8 lo, hi;
        #pragma unroll
        for (int j = 0; j < 8; ++j) { lo[j] = t[j]; hi[j] = t[8 + j]; }
        int sw = (c >> 2) & 1;
        bf16x8* dst = (bf16x8*)&lds2[p * 16];
        dst[sw] = lo; dst[1 - sw] = hi;
    }
    bf16x8 wf[5];
    #pragma unroll
    for (int i = 0; i < 5; ++i)
        #pragma unroll
        for (int j = 0; j < 8; ++j) {
            int kk = 32 * i + 8 * g + j;
            int tap = kk >> 4, ci = kk & 15;
            short v = 0;
            if (tap < 9) v = f2bf(k[(m * 16 + ci) * 9 + tap]);
            wf[i][j] = v;
        }
    int off[5];
    #pragma unroll
    for (int i = 0; i < 5; ++i) {
        int tap = 2 * i + (g >> 1);
        if (tap > 8) tap = 8;
        int kh = tap / 3, kw = tap - kh * 3;
        int col = m + kw;
        int o = (kh * 34 + col) * 32 + (g & 1) * 16;
        off[i] = o ^ ((col & 4) << 2);
    }
    __syncthreads();
    const char* ldsb = (const char*)lds2;
    const int coBase = g * 4;
    for (int hl8 = 0; hl8 < 8; ++hl8) {
        int hl = wv * 8 + hl8;
        int h = h0 + hl;
        bool hok = (h < HOUT);
        #pragma unroll
        for (int nh = 0; nh < 2; ++nh) {
            int wl = nh * 16;
            int tb = (hl * 34 + wl) * 32;
            f32x4 acc = {0.f, 0.f, 0.f, 0.f};
            #pragma unroll
            for (int i = 0; i < 5; ++i) {
                bf16x8 b = *(const bf16x8*)(ldsb + (tb + off[i]));
                acc = __builtin_amdgcn_mfma_f32_16x16x32_bf16(wf[i], b, acc, 0, 0, 0);
            }
            int w = w0 + wl + m;
            if (hok && w < WOUT) {
                float* op = out + h * WOUT + w;
                #pragma unroll
                for (int r = 0; r < 4; ++r)
                    op[(coBase + r) * PLANE_OUT] = acc[r];
            }
        }
    }
}

extern "C" void kernel_launch(void* const* d_in, const int* in_sizes, int n_in,
                              void* d_out, int out_size, void* d_ws, size_t ws_size,
                              hipStream_t stream) {
    const float* x = (const float*)d_in[0];
    const float* k = (const float*)d_in[1];
    float* out = (float*)d_out;
    const size_t need = (XT_U32 + WF_U32) * 4;   // 128 MiB xt + 5 KiB wf
    if (ws_size >= need) {
        unsigned* xt = (unsigned*)d_ws;
        unsigned* wfbuf = xt + XT_U32;
        wf_setup<<<dim3(1), dim3(64), 0, stream>>>(k, wfbuf);
        pack_gll<<<dim3(8192), dim3(512), 0, stream>>>(x, xt);
        conv3x3_mfma2<<<dim3(4096), dim3(512), 0, stream>>>(xt, wfbuf, out);
    } else if (ws_size >= WF_U32 * 4) {
        unsigned* wfbuf = (unsigned*)d_ws;
        wf_setup<<<dim3(1), dim3(64), 0, stream>>>(k, wfbuf);
        conv3x3_fused<<<dim3(4096), dim3(512), 0, stream>>>(x, wfbuf, out);
    } else {
        conv3x3_mfma<<<dim3(4096), dim3(256), 0, stream>>>(x, k, out);
    }
}

// Round 16
// 149.239 us; speedup vs baseline: 1.5499x; 1.5499x over previous
//
#include <hip/hip_runtime.h>

// Fused single-pass 3x3 VALID conv via bf16 MFMA implicit GEMM.
// x:(16,2048,2048) fp32, k:(16,16,3,3) fp32 -> out:(16,2046,2046) fp32
// 1024-thread blocks: each thread does AT MOST ONE stage task (8 plane-
// strided f32x4 loads -> 16 pk2 -> 2x ds_write_b128, XOR-swizzled), so the
// staging critical path is a single HBM latency; 39KB LDS x 2 blocks/CU
// = 32 waves/CU. Compute: 5x mfma_16x16x32_bf16 per 16x16 sub-tile
// (R8/R9-verified contract, 2 rows per wave).
// Weight fragments precomputed once into d_ws.

#define HIN   2048
#define WIN   2048
#define HOUT  2046
#define WOUT  2046
#define PLANE_IN  (HIN * WIN)
#define PLANE_OUT (HOUT * WOUT)
#define TR 34
#define TC 36                          // padded staging stride (cols)
#define NQTASK (TR * 9 * 2)            // 612: 34 rows x 9 w-quads x 2 ci-halves
#define WF_U32 (5 * 64 * 4)            // weight-frag buffer (5 KiB)

typedef __attribute__((ext_vector_type(8))) short bf16x8;
typedef __attribute__((ext_vector_type(4))) float f32x4;
typedef __attribute__((ext_vector_type(4))) unsigned u32x4;
typedef f32x4 __attribute__((aligned(4))) f32x4_u;

static __device__ __forceinline__ short f2bf(float f) {
    unsigned u = __float_as_uint(f);
    return (short)((u + 0x7FFFu + ((u >> 16) & 1u)) >> 16);   // RNE
}
static __device__ __forceinline__ unsigned pk2(float lo, float hi) {
    unsigned a = __float_as_uint(lo);
    unsigned b = __float_as_uint(hi);
    a = (a + 0x7FFFu + ((a >> 16) & 1u)) >> 16;
    b = (b + 0x7FFFu + ((b >> 16) & 1u)) & 0xFFFF0000u;
    return a | b;
}

// ---------------- setup: per-lane MFMA weight fragments ----------------------
__global__ __launch_bounds__(64)
void wf_setup(const float* __restrict__ k, unsigned* __restrict__ wfbuf) {
    int lane = threadIdx.x;
    int m = lane & 15, g = lane >> 4;
    #pragma unroll
    for (int i = 0; i < 5; ++i) {
        u32x4 q;
        #pragma unroll
        for (int jj = 0; jj < 4; ++jj) {
            unsigned r = 0;
            #pragma unroll
            for (int e = 0; e < 2; ++e) {
                int kk  = 32 * i + 8 * g + 2 * jj + e;
                int tap = kk >> 4;
                int ci  = kk & 15;
                unsigned v = 0;
                if (tap < 9) v = (unsigned short)f2bf(k[(m * 16 + ci) * 9 + tap]);
                r |= v << (16 * e);
            }
            q[jj] = r;
        }
        *(u32x4*)(wfbuf + (i * 64 + lane) * 4) = q;
    }
}

// ---------------- stage task body (shared by both fused kernels) -------------
#define STAGE_TASK_BODY(T, LDSPTR, W0, H0)                                    \
    do {                                                                      \
        int t   = (T);                                                        \
        int q   = t % 9;                                                      \
        int r2  = t / 9;                                                      \
        int cih = r2 & 1;                                                     \
        int row = r2 >> 1;                                                    \
        int c   = 4 * q;                                                      \
        int w   = (W0) + c; if (w > WIN - 4) w = WIN - 4;                     \
        const float* gp = x + (size_t)(cih * 8) * PLANE_IN                    \
                            + (size_t)((H0) + row) * WIN + w;                 \
        f32x4 f0 = *(const f32x4*)(gp + 0 * (size_t)PLANE_IN);                \
        f32x4 f1 = *(const f32x4*)(gp + 1 * (size_t)PLANE_IN);                \
        f32x4 f2 = *(const f32x4*)(gp + 2 * (size_t)PLANE_IN);                \
        f32x4 f3 = *(const f32x4*)(gp + 3 * (size_t)PLANE_IN);                \
        f32x4 f4 = *(const f32x4*)(gp + 4 * (size_t)PLANE_IN);                \
        f32x4 f5 = *(const f32x4*)(gp + 5 * (size_t)PLANE_IN);                \
        f32x4 f6 = *(const f32x4*)(gp + 6 * (size_t)PLANE_IN);                \
        f32x4 f7 = *(const f32x4*)(gp + 7 * (size_t)PLANE_IN);                \
        int a = ((row * TC + c) * 32 + cih * 16) ^ ((c & 4) << 2);            \
        u32x4 ch;                                                             \
        ch[0] = pk2(f0[0], f1[0]); ch[1] = pk2(f2[0], f3[0]);                 \
        ch[2] = pk2(f4[0], f5[0]); ch[3] = pk2(f6[0], f7[0]);                 \
        *(u32x4*)((char*)(LDSPTR) + a)      = ch;                             \
        ch[0] = pk2(f0[1], f1[1]); ch[1] = pk2(f2[1], f3[1]);                 \
        ch[2] = pk2(f4[1], f5[1]); ch[3] = pk2(f6[1], f7[1]);                 \
        *(u32x4*)((char*)(LDSPTR) + a + 32) = ch;                             \
        ch[0] = pk2(f0[2], f1[2]); ch[1] = pk2(f2[2], f3[2]);                 \
        ch[2] = pk2(f4[2], f5[2]); ch[3] = pk2(f6[2], f7[2]);                 \
        *(u32x4*)((char*)(LDSPTR) + a + 64) = ch;                             \
        ch[0] = pk2(f0[3], f1[3]); ch[1] = pk2(f2[3], f3[3]);                 \
        ch[2] = pk2(f4[3], f5[3]); ch[3] = pk2(f6[3], f7[3]);                 \
        *(u32x4*)((char*)(LDSPTR) + a + 96) = ch;                             \
    } while (0)

// ---------------- primary: 1024-thread fused conv ----------------
__global__ __launch_bounds__(1024, 2)
void conv3x3_fused1k(const float* __restrict__ x,
                     const unsigned* __restrict__ wfbuf,
                     float* __restrict__ out) {
    __shared__ unsigned lds[TR * TC * 8];   // 39168 B

    const int tid  = threadIdx.x;
    const int lane = tid & 63;
    const int wv   = tid >> 6;              // 0..15
    const int m    = lane & 15;
    const int g    = lane >> 4;

    int bid = blockIdx.x;                      // 4096 blocks (64 x 64 tiles)
    int swz = (bid & 7) * 512 + (bid >> 3);    // XCD-chunked (4096 % 8 == 0)
    int h0 = (swz >> 6) * 32; if (h0 > HOUT - 32) h0 = HOUT - 32;  // 2014
    int w0 = (swz & 63) * 32;

    // ---- stage: each thread does at most ONE task (single latency exposure)
    if (tid < NQTASK) STAGE_TASK_BODY(tid, lds, w0, h0);

    // ---- weight fragments: 5 coalesced 16B loads (L2-hot) ----
    bf16x8 wf[5];
    #pragma unroll
    for (int i = 0; i < 5; ++i)
        wf[i] = *(const bf16x8*)(wfbuf + (i * 64 + lane) * 4);

    // ---- per-lane A-fragment LDS byte offsets ----
    int off[5];
    #pragma unroll
    for (int i = 0; i < 5; ++i) {
        int tap = 2 * i + (g >> 1);
        if (tap > 8) tap = 8;                   // dead K (weights are 0)
        int kh = tap / 3;
        int kw = tap - kh * 3;
        int col = m + kw;
        int o = (kh * TC + col) * 32 + (g & 1) * 16;
        off[i] = o ^ ((col & 4) << 2);          // matches staging swizzle
    }

    __syncthreads();

    const char* ldsb = (const char*)lds;

    #pragma unroll
    for (int hl2 = 0; hl2 < 2; ++hl2) {
        int hl = wv * 2 + hl2;                  // 16 waves x 2 rows = 32 rows
        int h  = h0 + hl;                       // always < HOUT (h0 <= 2014)
        #pragma unroll
        for (int nh = 0; nh < 2; ++nh) {
            int wl = nh * 16;
            int tb = (hl * TC + wl) * 32;
            f32x4 acc = {0.f, 0.f, 0.f, 0.f};
            #pragma unroll
            for (int i = 0; i < 5; ++i) {
                bf16x8 a = *(const bf16x8*)(ldsb + (tb + off[i]));
                acc = __builtin_amdgcn_mfma_f32_16x16x32_bf16(a, wf[i], acc, 0, 0, 0);
            }
            // D: row = g*4+r = spatial, col = m = co  ->  float4 store
            int w = w0 + wl + g * 4;
            float* op = out + m * (size_t)PLANE_OUT + (size_t)h * WOUT + w;
            if (w + 3 < WOUT) {
                *(f32x4_u*)op = acc;
            } else {
                #pragma unroll
                for (int r = 0; r < 4; ++r)
                    if (w + r < WOUT) op[r] = acc[r];
            }
        }
    }
}

// ---------------- fallback A: 512-thread fused (R9, proven 152us) ------------
__global__ __launch_bounds__(512, 8)
void conv3x3_fused(const float* __restrict__ x,
                   const unsigned* __restrict__ wfbuf,
                   float* __restrict__ out) {
    __shared__ unsigned lds[TR * TC * 8];

    const int tid  = threadIdx.x;
    const int lane = tid & 63;
    const int wv   = tid >> 6;
    const int m    = lane & 15;
    const int g    = lane >> 4;

    int bid = blockIdx.x;
    int swz = (bid & 7) * 512 + (bid >> 3);
    int h0 = (swz >> 6) * 32; if (h0 > HOUT - 32) h0 = HOUT - 32;
    int w0 = (swz & 63) * 32;

    STAGE_TASK_BODY(tid, lds, w0, h0);
    if (tid < NQTASK - 512) STAGE_TASK_BODY(512 + tid, lds, w0, h0);

    bf16x8 wf[5];
    #pragma unroll
    for (int i = 0; i < 5; ++i)
        wf[i] = *(const bf16x8*)(wfbuf + (i * 64 + lane) * 4);

    int off[5];
    #pragma unroll
    for (int i = 0; i < 5; ++i) {
        int tap = 2 * i + (g >> 1);
        if (tap > 8) tap = 8;
        int kh = tap / 3;
        int kw = tap - kh * 3;
        int col = m + kw;
        int o = (kh * TC + col) * 32 + (g & 1) * 16;
        off[i] = o ^ ((col & 4) << 2);
    }

    __syncthreads();

    const char* ldsb = (const char*)lds;

    #pragma unroll
    for (int hl4 = 0; hl4 < 4; ++hl4) {
        int hl = wv * 4 + hl4;
        int h  = h0 + hl;
        #pragma unroll
        for (int nh = 0; nh < 2; ++nh) {
            int wl = nh * 16;
            int tb = (hl * TC + wl) * 32;
            f32x4 acc = {0.f, 0.f, 0.f, 0.f};
            #pragma unroll
            for (int i = 0; i < 5; ++i) {
                bf16x8 a = *(const bf16x8*)(ldsb + (tb + off[i]));
                acc = __builtin_amdgcn_mfma_f32_16x16x32_bf16(a, wf[i], acc, 0, 0, 0);
            }
            int w = w0 + wl + g * 4;
            float* op = out + m * (size_t)PLANE_OUT + (size_t)h * WOUT + w;
            if (w + 3 < WOUT) {
                *(f32x4_u*)op = acc;
            } else {
                #pragma unroll
                for (int r = 0; r < 4; ++r)
                    if (w + r < WOUT) op[r] = acc[r];
            }
        }
    }
}

// ---------------- fallback B (no workspace): fp32-staged single pass ---------
__global__ __launch_bounds__(256, 4)
void conv3x3_mfma(const float* __restrict__ x,
                  const float* __restrict__ k,
                  float* __restrict__ out) {
    __shared__ short lds2[TR * 34 * 16];
    const int tid  = threadIdx.x;
    const int lane = tid & 63;
    const int wv   = tid >> 6;
    const int m    = lane & 15;
    const int g    = lane >> 4;
    int bid = blockIdx.x;
    int swz = (bid & 7) * 512 + (bid >> 3);
    int h0 = (swz >> 6) * 32;
    int w0 = (swz & 63) * 32;
    for (int p = tid; p < TR * 34; p += 256) {
        int r = p / 34, c = p - r * 34;
        int hh = h0 + r; if (hh > HIN - 1) hh = HIN - 1;
        int ww = w0 + c; if (ww > WIN - 1) ww = WIN - 1;
        const float* gp = x + hh * WIN + ww;
        short t[16];
        #pragma unroll
        for (int ci = 0; ci < 16; ++ci) t[ci] = f2bf(gp[ci * PLANE_IN]);
        bf16x8 lo, hi;
        #pragma unroll
        for (int j = 0; j < 8; ++j) { lo[j] = t[j]; hi[j] = t[8 + j]; }
        int sw = (c >> 2) & 1;
        bf16x8* dst = (bf16x8*)&lds2[p * 16];
        dst[sw] = lo; dst[1 - sw] = hi;
    }
    bf16x8 wf[5];
    #pragma unroll
    for (int i = 0; i < 5; ++i)
        #pragma unroll
        for (int j = 0; j < 8; ++j) {
            int kk = 32 * i + 8 * g + j;
            int tap = kk >> 4, ci = kk & 15;
            short v = 0;
            if (tap < 9) v = f2bf(k[(m * 16 + ci) * 9 + tap]);
            wf[i][j] = v;
        }
    int off[5];
    #pragma unroll
    for (int i = 0; i < 5; ++i) {
        int tap = 2 * i + (g >> 1);
        if (tap > 8) tap = 8;
        int kh = tap / 3, kw = tap - kh * 3;
        int col = m + kw;
        int o = (kh * 34 + col) * 32 + (g & 1) * 16;
        off[i] = o ^ ((col & 4) << 2);
    }
    __syncthreads();
    const char* ldsb = (const char*)lds2;
    const int coBase = g * 4;
    for (int hl8 = 0; hl8 < 8; ++hl8) {
        int hl = wv * 8 + hl8;
        int h = h0 + hl;
        bool hok = (h < HOUT);
        #pragma unroll
        for (int nh = 0; nh < 2; ++nh) {
            int wl = nh * 16;
            int tb = (hl * 34 + wl) * 32;
            f32x4 acc = {0.f, 0.f, 0.f, 0.f};
            #pragma unroll
            for (int i = 0; i < 5; ++i) {
                bf16x8 b = *(const bf16x8*)(ldsb + (tb + off[i]));
                acc = __builtin_amdgcn_mfma_f32_16x16x32_bf16(wf[i], b, acc, 0, 0, 0);
            }
            int w = w0 + wl + m;
            if (hok && w < WOUT) {
                float* op = out + h * WOUT + w;
                #pragma unroll
                for (int r = 0; r < 4; ++r)
                    op[(coBase + r) * PLANE_OUT] = acc[r];
            }
        }
    }
}

extern "C" void kernel_launch(void* const* d_in, const int* in_sizes, int n_in,
                              void* d_out, int out_size, void* d_ws, size_t ws_size,
                              hipStream_t stream) {
    const float* x = (const float*)d_in[0];
    const float* k = (const float*)d_in[1];
    float* out = (float*)d_out;
    if (ws_size >= WF_U32 * 4) {
        unsigned* wfbuf = (unsigned*)d_ws;
        wf_setup<<<dim3(1), dim3(64), 0, stream>>>(k, wfbuf);
        conv3x3_fused1k<<<dim3(4096), dim3(1024), 0, stream>>>(x, wfbuf, out);
    } else {
        conv3x3_mfma<<<dim3(4096), dim3(256), 0, stream>>>(x, k, out);
    }
}